// Round 5
// baseline (114.087 us; speedup 1.0000x reference)
//
#include <hip/hip_runtime.h>
#include <math.h>

#define RES     512
#define NBLOB   2048
#define TILE_W  32
#define TILE_H  8
#define TX_N    (RES / TILE_W)   // 16
#define TY_N    (RES / TILE_H)   // 64
#define NTILE   (TX_N * TY_N)    // 1024
#define PRE_STRIDE 16            // floats per blob in pre[]: 9 params + 3 pad + 4 bbox
#define TB_STRIDE  12            // floats per blob in tilebuf: [px py a b][d e cr cg][cb 0 0 0]
#define TILE_CAP   NBLOB
#define CULL_R5 4.9956f          // sqrt(18)/K : cutoff where g < 2^-18 (err <= 2048*3.8e-6)

__device__ __forceinline__ float fast_exp2(float x) {
#if __has_builtin(__builtin_amdgcn_exp2f)
    return __builtin_amdgcn_exp2f(x);
#else
    return exp2f(x);
#endif
}

// Per-blob preprocessing: fold rotation/scale/exp-constant into a 2x2 matrix
// (g = exp2(-(u^2+v^2)), K = sqrt(0.5*log2 e) folded in) + tile-space bbox.
__global__ __launch_bounds__(256) void pre_kernel(const float* __restrict__ blobs,
                                                  float* __restrict__ pre) {
    int i = blockIdx.x * blockDim.x + threadIdx.x;
    if (i >= NBLOB) return;
    const float* bp = blobs + i * 8;
    float posx = bp[0], posy = bp[1];
    float sx = bp[2], sy = bp[3];
    float rot = bp[4];
    float c = cosf(rot), s = sinf(rot);
    const float K = 0.84932184f;  // sqrt(0.5 * log2(e))
    float isx = K / sx, isy = K / sy;
    float* o = pre + i * PRE_STRIDE;
    o[0] = posx; o[1] = posy;
    o[2] = c * isx;   // a
    o[3] = s * isx;   // b
    o[4] = -s * isy;  // d
    o[5] = c * isy;   // e
    o[6] = bp[5]; o[7] = bp[6]; o[8] = bp[7];   // color
    o[9] = 0.f; o[10] = 0.f; o[11] = 0.f;

    float hx = CULL_R5 * sqrtf(c * c * sx * sx + s * s * sy * sy);
    float hy = CULL_R5 * sqrtf(s * s * sx * sx + c * c * sy * sy);
    int tx0 = max(0,        (int)floorf(((posx - hx) * RES - 0.5f) * (1.0f / TILE_W)));
    int tx1 = min(TX_N - 1, (int)floorf(((posx + hx) * RES - 0.5f) * (1.0f / TILE_W)));
    int ty0 = max(0,        (int)floorf(((posy - hy) * RES - 0.5f) * (1.0f / TILE_H)));
    int ty1 = min(TY_N - 1, (int)floorf(((posy + hy) * RES - 0.5f) * (1.0f / TILE_H)));
    int* ob = (int*)(o + 12);
    ob[0] = tx0; ob[1] = tx1; ob[2] = ty0; ob[3] = ty1;
}

// One block per tile: bbox-test all blobs, ballot-compact survivors' 12-float
// param records into this tile's contiguous region of tilebuf. Pad the count
// to a multiple of 8 with zero-blobs (u=v=0 -> g=1, color=0 -> contributes 0)
// so the splat loop needs no tail handling.
__global__ __launch_bounds__(256) void build_kernel(const float* __restrict__ pre,
                                                    float* __restrict__ tilebuf,
                                                    int* __restrict__ counts) {
    __shared__ int sh_cnt;
    const int tid = threadIdx.x;
    const int lane = tid & 63;
    if (tid == 0) sh_cnt = 0;
    __syncthreads();

    const int tx = blockIdx.x;
    const int ty = blockIdx.y;
    const int t = ty * TX_N + tx;
    float4* dst = (float4*)(tilebuf + (size_t)t * TILE_CAP * TB_STRIDE);

    for (int c = 0; c < NBLOB / 256; ++c) {
        const int j = c * 256 + tid;
        const int4 ob = *(const int4*)(pre + j * PRE_STRIDE + 12);
        const bool hit = (tx >= ob.x) & (tx <= ob.y) & (ty >= ob.z) & (ty <= ob.w);
        const unsigned long long mask = __ballot(hit);
        const int total = __popcll(mask);
        int base = 0;
        if (lane == 0 && total > 0) base = atomicAdd(&sh_cnt, total);
        base = __builtin_amdgcn_readfirstlane(base);
        if (hit) {
            const int pos = base + __popcll(mask & ((1ull << lane) - 1ull));
            const float4* p4 = (const float4*)(pre + j * PRE_STRIDE);
            dst[pos * 3 + 0] = p4[0];   // px py a b
            dst[pos * 3 + 1] = p4[1];   // d e cr cg
            dst[pos * 3 + 2] = p4[2];   // cb 0 0 0
        }
    }
    __syncthreads();

    const int n = sh_cnt;
    const int pad = (8 - (n & 7)) & 7;
    if (tid < pad) {
        const float4 z = make_float4(0.f, 0.f, 0.f, 0.f);
        dst[(n + tid) * 3 + 0] = z;
        dst[(n + tid) * 3 + 1] = z;
        dst[(n + tid) * 3 + 2] = z;
    }
    if (tid == 0) counts[t] = n + pad;
}

// One block per 32x8 tile, 1 px/thread. Params come from the tile's compacted
// region at loop-linear wave-uniform addresses -> scalar s_load batches on the
// SMEM pipe (no LDS bus, no dependent index chain). Inner unroll-8 is exact
// (count padded to x8) so loads pipeline 8-deep.
__global__ __launch_bounds__(256) void splat_kernel(const float* __restrict__ tilebuf,
                                                    const int* __restrict__ counts,
                                                    float* __restrict__ out) {
    const int tid = threadIdx.x;
    const int tx = blockIdx.x;
    const int ty = blockIdx.y;
    const int t = ty * TX_N + tx;
    const int n = counts[t];
    const float4* tp = (const float4*)(tilebuf + (size_t)t * TILE_CAP * TB_STRIDE);

    const int x = tx * TILE_W + (tid & 31);
    const int y = ty * TILE_H + (tid >> 5);
    const float fx = (x + 0.5f) * (1.0f / RES);
    const float fy = (y + 0.5f) * (1.0f / RES);

    float ar = 0.f, ag = 0.f, ab = 0.f;

    for (int k0 = 0; k0 < n; k0 += 8) {
        #pragma unroll
        for (int kk = 0; kk < 8; ++kk) {
            const int k = k0 + kk;
            const float4 q0 = tp[k * 3 + 0];
            const float4 q1 = tp[k * 3 + 1];
            const float  cb = tp[k * 3 + 2].x;
            const float dx = fx - q0.x;
            const float dy = fy - q0.y;
            const float u = q0.z * dx + q0.w * dy;
            const float v = q1.x * dx + q1.y * dy;
            const float g = fast_exp2(-(u * u + v * v));
            ar += g * q1.z;
            ag += g * q1.w;
            ab += g * cb;
        }
    }

    const int base = (y * RES + x) * 3;
    out[base + 0] = ar;
    out[base + 1] = ag;
    out[base + 2] = ab;
}

// Fallback (ws too small for tilebuf): R4-style fused cull+LDS-stage splat.
__global__ __launch_bounds__(256) void splat_fallback(const float* __restrict__ pre,
                                                      float* __restrict__ out) {
    __shared__ int sh_cnt;
    __shared__ int sh_list[NBLOB];
    const int tid = threadIdx.x;
    if (tid == 0) sh_cnt = 0;
    __syncthreads();
    const int tx = blockIdx.x, ty = blockIdx.y;
    const int lane = tid & 63;
    for (int j0 = 0; j0 < NBLOB; j0 += 256) {
        const int j = j0 + tid;
        const int4 ob = *(const int4*)(pre + j * PRE_STRIDE + 12);
        const bool hit = (tx >= ob.x) & (tx <= ob.y) & (ty >= ob.z) & (ty <= ob.w);
        const unsigned long long mask = __ballot(hit);
        const int total = __popcll(mask);
        int base = 0;
        if (lane == 0 && total > 0) base = atomicAdd(&sh_cnt, total);
        base = __builtin_amdgcn_readfirstlane(base);
        if (hit) sh_list[base + __popcll(mask & ((1ull << lane) - 1ull))] = j;
    }
    __syncthreads();
    const int n = sh_cnt;
    const int x = tx * TILE_W + (tid & 31);
    const int y = ty * TILE_H + (tid >> 5);
    const float fx = (x + 0.5f) * (1.0f / RES);
    const float fy = (y + 0.5f) * (1.0f / RES);
    float ar = 0.f, ag = 0.f, ab = 0.f;
    for (int k = 0; k < n; ++k) {
        const int j = __builtin_amdgcn_readfirstlane(sh_list[k]);
        const float* p = pre + j * PRE_STRIDE;
        const float dx = fx - p[0];
        const float dy = fy - p[1];
        const float u = p[2] * dx + p[3] * dy;
        const float v = p[4] * dx + p[5] * dy;
        const float g = fast_exp2(-(u * u + v * v));
        ar += g * p[6]; ag += g * p[7]; ab += g * p[8];
    }
    const int base = (y * RES + x) * 3;
    out[base + 0] = ar; out[base + 1] = ag; out[base + 2] = ab;
}

extern "C" void kernel_launch(void* const* d_in, const int* in_sizes, int n_in,
                              void* d_out, int out_size, void* d_ws, size_t ws_size,
                              hipStream_t stream) {
    const float* blobs = (const float*)d_in[0];
    float* out = (float*)d_out;

    char* ws = (char*)d_ws;
    float* pre = (float*)ws;
    size_t off = (size_t)NBLOB * PRE_STRIDE * 4;         // 128 KB
    int* counts = (int*)(ws + off); off += NTILE * 4;    // 4 KB
    off = (off + 255) & ~(size_t)255;
    float* tilebuf = (float*)(ws + off);
    size_t need = off + (size_t)NTILE * TILE_CAP * TB_STRIDE * 4;  // ~101 MB

    hipLaunchKernelGGL(pre_kernel, dim3(NBLOB / 256), dim3(256), 0, stream,
                       blobs, pre);
    if (ws_size >= need) {
        hipLaunchKernelGGL(build_kernel, dim3(TX_N, TY_N), dim3(256), 0, stream,
                           pre, tilebuf, counts);
        hipLaunchKernelGGL(splat_kernel, dim3(TX_N, TY_N), dim3(256), 0, stream,
                           tilebuf, counts, out);
    } else {
        hipLaunchKernelGGL(splat_fallback, dim3(TX_N, TY_N), dim3(256), 0, stream,
                           pre, out);
    }
}

// Round 6
// 94.264 us; speedup vs baseline: 1.2103x; 1.2103x over previous
//
#include <hip/hip_runtime.h>
#include <hip/hip_fp16.h>
#include <math.h>

#define RES     512
#define NBLOB   2048
#define TILE_W  32
#define TILE_H  32
#define TX_N    (RES / TILE_W)   // 16
#define TY_N    (RES / TILE_H)   // 16
#define NCHUNK  4                // blob-chunks per tile (occupancy lever: 1024 blocks)
#define CAP     512              // max blobs per chunk (= ceil(NBLOB/NCHUNK))
#define PRE_STRIDE 16            // floats per blob in pre[]: 9 params + 3 pad + 4 bbox
#define CULL_R5 4.9956f          // sqrt(18)/K : cutoff where g < 2^-18

union HF { __half2 h; float f; };

__device__ __forceinline__ float fast_exp2(float x) {
#if __has_builtin(__builtin_amdgcn_exp2f)
    return __builtin_amdgcn_exp2f(x);
#else
    return exp2f(x);
#endif
}

// Per-blob preprocessing: fold rotation/scale/exp-constant into a 2x2 matrix
// (g = exp2(-(u^2+v^2)), K = sqrt(0.5*log2 e) folded in) + 32x32-tile bbox.
__global__ __launch_bounds__(256) void pre_kernel(const float* __restrict__ blobs,
                                                  float* __restrict__ pre) {
    int i = blockIdx.x * blockDim.x + threadIdx.x;
    if (i >= NBLOB) return;
    const float* bp = blobs + i * 8;
    float posx = bp[0], posy = bp[1];
    float sx = bp[2], sy = bp[3];
    float rot = bp[4];
    float c = cosf(rot), s = sinf(rot);
    const float K = 0.84932184f;  // sqrt(0.5 * log2(e))
    float isx = K / sx, isy = K / sy;
    float* o = pre + i * PRE_STRIDE;
    o[0] = posx; o[1] = posy;
    o[2] = c * isx;   // a
    o[3] = s * isx;   // b
    o[4] = -s * isy;  // d
    o[5] = c * isy;   // e
    o[6] = bp[5]; o[7] = bp[6]; o[8] = bp[7];
    o[9] = 0.f; o[10] = 0.f; o[11] = 0.f;

    float hx = CULL_R5 * sqrtf(c * c * sx * sx + s * s * sy * sy);
    float hy = CULL_R5 * sqrtf(s * s * sx * sx + c * c * sy * sy);
    int tx0 = max(0,        (int)floorf(((posx - hx) * RES - 0.5f) * (1.0f / TILE_W)));
    int tx1 = min(TX_N - 1, (int)floorf(((posx + hx) * RES - 0.5f) * (1.0f / TILE_W)));
    int ty0 = max(0,        (int)floorf(((posy - hy) * RES - 0.5f) * (1.0f / TILE_H)));
    int ty1 = min(TY_N - 1, (int)floorf(((posy + hy) * RES - 0.5f) * (1.0f / TILE_H)));
    int* ob = (int*)(o + 12);
    ob[0] = tx0; ob[1] = tx1; ob[2] = ty0; ob[3] = ty1;
}

// out is re-poisoned 0xAA before every timed launch -> explicit zero pass
// (kernel, not hipMemsetAsync, to be graph-capture-bulletproof).
__global__ __launch_bounds__(256) void zero_kernel(float4* __restrict__ out) {
    out[blockIdx.x * 256 + threadIdx.x] = make_float4(0.f, 0.f, 0.f, 0.f);
}

// One block per (32x32 tile, blob-chunk). 4 px/thread (rows y0+{0,8,16,24})
// amortizes the per-blob LDS broadcast over 4x the pixels; NCHUNK=4 blocks
// per tile restores 16 waves/CU. Deterministic ballot-prefix partition of the
// tile's survivor list (identical in all 4 sibling blocks); results merged
// via fp32 global atomicAdd into the pre-zeroed image.
__global__ __launch_bounds__(256) void splat_kernel(const float* __restrict__ pre,
                                                    float* __restrict__ out) {
    __shared__ int sh_cnt[32];                    // per (iter, wave) survivor count
    __shared__ unsigned long long sh_mask[32];    // per (iter, wave) hit ballot
    __shared__ float4 sh_rec[2 * CAP];            // packed 32 B records

    const int tid  = threadIdx.x;
    const int lane = tid & 63;
    const int w    = tid >> 6;                    // wave id 0..3
    const int tx = blockIdx.x, ty = blockIdx.y, ch = blockIdx.z;

    // ---- pass 1: ballot-count all 2048 bboxes vs this tile ----
    #pragma unroll
    for (int i = 0; i < NBLOB / 256; ++i) {
        const int j = i * 256 + tid;
        const int4 ob = *(const int4*)(pre + j * PRE_STRIDE + 12);
        const bool hit = (tx >= ob.x) & (tx <= ob.y) & (ty >= ob.z) & (ty <= ob.w);
        const unsigned long long m = __ballot(hit);
        if (lane == 0) { sh_cnt[i * 4 + w] = __popcll(m); sh_mask[i * 4 + w] = m; }
    }
    __syncthreads();

    // ---- deterministic prefix: base offset for each of my 8 (iter, w) slots ----
    int base[8];
    int n = 0;
    #pragma unroll
    for (int k = 0; k < 32; ++k) {
        if ((k & 3) == w) base[k >> 2] = n;
        n += sh_cnt[k];
    }
    const int lo = (ch * n) / NCHUNK;
    const int hi = ((ch + 1) * n) / NCHUNK;       // my slice [lo, hi), <= CAP

    // ---- pass 2: stage my slice's params (32 B packed) into LDS ----
    #pragma unroll
    for (int i = 0; i < NBLOB / 256; ++i) {
        const unsigned long long m = sh_mask[i * 4 + w];
        if ((m >> lane) & 1ull) {
            const int pos = base[i] + __popcll(m & ((1ull << lane) - 1ull));
            if (pos >= lo && pos < hi) {
                const float* p = pre + (i * 256 + tid) * PRE_STRIDE;
                HF c01, c2;
                c01.h = __floats2half2_rn(p[6], p[7]);
                c2.h  = __floats2half2_rn(p[8], 0.f);
                sh_rec[(pos - lo) * 2 + 0] = make_float4(p[0], p[1], p[2], p[3]);
                sh_rec[(pos - lo) * 2 + 1] = make_float4(p[4], p[5], c01.f, c2.f);
            }
        }
    }
    __syncthreads();

    const int my_n = hi - lo;
    const int x  = tx * TILE_W + (tid & 31);
    const int y0 = ty * TILE_H + (tid >> 5);      // rows y0, y0+8, y0+16, y0+24
    const float fx  = (x + 0.5f) * (1.0f / RES);
    const float fy0 = (y0 + 0.5f) * (1.0f / RES);

    float ar0 = 0.f, ag0 = 0.f, ab0 = 0.f;
    float ar1 = 0.f, ag1 = 0.f, ab1 = 0.f;
    float ar2 = 0.f, ag2 = 0.f, ab2 = 0.f;
    float ar3 = 0.f, ag3 = 0.f, ab3 = 0.f;

    #pragma unroll 2
    for (int k = 0; k < my_n; ++k) {
        const float4 q0 = sh_rec[k * 2 + 0];      // px py a b
        const float4 q1 = sh_rec[k * 2 + 1];      // d e (cr,cg)h2 (cb,0)h2
        const float dx  = fx - q0.x;
        const float dyb = fy0 - q0.y;
        const float tu = q0.z * dx;
        const float tv = q1.x * dx;
        HF c01, c2; c01.f = q1.z; c2.f = q1.w;
        const float cr = __low2float(c01.h);
        const float cg = __high2float(c01.h);
        const float cb = __low2float(c2.h);
        float u, v, g;
        u = fmaf(q0.w, dyb, tu);
        v = fmaf(q1.y, dyb, tv);
        g = fast_exp2(-(u * u + v * v));
        ar0 += g * cr; ag0 += g * cg; ab0 += g * cb;
        u = fmaf(q0.w, dyb + ( 8.0f / RES), tu);
        v = fmaf(q1.y, dyb + ( 8.0f / RES), tv);
        g = fast_exp2(-(u * u + v * v));
        ar1 += g * cr; ag1 += g * cg; ab1 += g * cb;
        u = fmaf(q0.w, dyb + (16.0f / RES), tu);
        v = fmaf(q1.y, dyb + (16.0f / RES), tv);
        g = fast_exp2(-(u * u + v * v));
        ar2 += g * cr; ag2 += g * cg; ab2 += g * cb;
        u = fmaf(q0.w, dyb + (24.0f / RES), tu);
        v = fmaf(q1.y, dyb + (24.0f / RES), tv);
        g = fast_exp2(-(u * u + v * v));
        ar3 += g * cr; ag3 += g * cg; ab3 += g * cb;
    }

    int b0 = ((y0 +  0) * RES + x) * 3;
    atomicAdd(&out[b0 + 0], ar0); atomicAdd(&out[b0 + 1], ag0); atomicAdd(&out[b0 + 2], ab0);
    int b1 = ((y0 +  8) * RES + x) * 3;
    atomicAdd(&out[b1 + 0], ar1); atomicAdd(&out[b1 + 1], ag1); atomicAdd(&out[b1 + 2], ab1);
    int b2 = ((y0 + 16) * RES + x) * 3;
    atomicAdd(&out[b2 + 0], ar2); atomicAdd(&out[b2 + 1], ag2); atomicAdd(&out[b2 + 2], ab2);
    int b3 = ((y0 + 24) * RES + x) * 3;
    atomicAdd(&out[b3 + 0], ar3); atomicAdd(&out[b3 + 1], ag3); atomicAdd(&out[b3 + 2], ab3);
}

extern "C" void kernel_launch(void* const* d_in, const int* in_sizes, int n_in,
                              void* d_out, int out_size, void* d_ws, size_t ws_size,
                              hipStream_t stream) {
    const float* blobs = (const float*)d_in[0];
    float* out = (float*)d_out;
    float* pre = (float*)d_ws;   // NBLOB * 16 floats = 128 KB

    hipLaunchKernelGGL(pre_kernel, dim3(NBLOB / 256), dim3(256), 0, stream,
                       blobs, pre);
    // out_size = 512*512*3 = 786432 floats = 196608 float4 = 768 blocks x 256
    hipLaunchKernelGGL(zero_kernel, dim3(out_size / 1024), dim3(256), 0, stream,
                       (float4*)out);
    hipLaunchKernelGGL(splat_kernel, dim3(TX_N, TY_N, NCHUNK), dim3(256), 0,
                       stream, pre, out);
}

// Round 7
// 92.844 us; speedup vs baseline: 1.2288x; 1.0153x over previous
//
#include <hip/hip_runtime.h>
#include <hip/hip_fp16.h>
#include <math.h>

#define RES     512
#define NBLOB   2048
#define TILE_W  32
#define TILE_H  32
#define TX_N    (RES / TILE_W)   // 16
#define TY_N    (RES / TILE_H)   // 16
#define NCHUNK  8                // blob-chunks per tile -> 2048 blocks
#define CAP     256              // slice <= ceil(NBLOB/NCHUNK) = 256 by construction
#define PRE_STRIDE 16            // floats per blob in pre[]: 9 params + 3 pad + 4 bbox
#define IMG_FLOATS (RES * RES * 3)
#define CULL_R5 4.9956f          // sqrt(18)/K : cutoff where g < 2^-18

union HF { __half2 h; float f; };

__device__ __forceinline__ float fast_exp2(float x) {
#if __has_builtin(__builtin_amdgcn_exp2f)
    return __builtin_amdgcn_exp2f(x);
#else
    return exp2f(x);
#endif
}

// Fold rotation/scale/exp-constant into a 2x2 matrix (g = exp2(-(u^2+v^2)),
// K = sqrt(0.5*log2 e) folded in) + 32x32-tile bbox of the cull ellipse.
__global__ __launch_bounds__(256) void pre_kernel(const float* __restrict__ blobs,
                                                  float* __restrict__ pre) {
    int i = blockIdx.x * blockDim.x + threadIdx.x;
    if (i >= NBLOB) return;
    const float* bp = blobs + i * 8;
    float posx = bp[0], posy = bp[1];
    float sx = bp[2], sy = bp[3];
    float rot = bp[4];
    float c = cosf(rot), s = sinf(rot);
    const float K = 0.84932184f;  // sqrt(0.5 * log2(e))
    float isx = K / sx, isy = K / sy;
    float* o = pre + i * PRE_STRIDE;
    o[0] = posx; o[1] = posy;
    o[2] = c * isx;   // a
    o[3] = s * isx;   // b
    o[4] = -s * isy;  // d
    o[5] = c * isy;   // e
    o[6] = bp[5]; o[7] = bp[6]; o[8] = bp[7];
    o[9] = 0.f; o[10] = 0.f; o[11] = 0.f;

    float hx = CULL_R5 * sqrtf(c * c * sx * sx + s * s * sy * sy);
    float hy = CULL_R5 * sqrtf(s * s * sx * sx + c * c * sy * sy);
    int tx0 = max(0,        (int)floorf(((posx - hx) * RES - 0.5f) * (1.0f / TILE_W)));
    int tx1 = min(TX_N - 1, (int)floorf(((posx + hx) * RES - 0.5f) * (1.0f / TILE_W)));
    int ty0 = max(0,        (int)floorf(((posy - hy) * RES - 0.5f) * (1.0f / TILE_H)));
    int ty1 = min(TY_N - 1, (int)floorf(((posy + hy) * RES - 0.5f) * (1.0f / TILE_H)));
    int* ob = (int*)(o + 12);
    ob[0] = tx0; ob[1] = tx1; ob[2] = ty0; ob[3] = ty1;
}

// One block per (32x32 tile, 1/8 of its survivor list). 4 px/thread amortizes
// the per-blob LDS broadcast; plain stores into this chunk's private partial
// image (no atomics, no zeroing). Deterministic ballot-prefix slice so the 8
// sibling blocks partition the list exactly.
__global__ __launch_bounds__(256, 8) void splat_kernel(const float* __restrict__ pre,
                                                       float* __restrict__ partial) {
    __shared__ int sh_cnt[32];                    // per (iter, wave) survivor count
    __shared__ unsigned long long sh_mask[32];    // per (iter, wave) hit ballot
    __shared__ float4 sh_rec[2 * (CAP + 4)];      // packed 32 B records + pad

    const int tid  = threadIdx.x;
    const int lane = tid & 63;
    const int w    = tid >> 6;                    // wave id 0..3
    const int tx = blockIdx.x, ty = blockIdx.y, ch = blockIdx.z;

    // ---- pass 1: ballot-count all 2048 bboxes vs this tile ----
    #pragma unroll
    for (int i = 0; i < NBLOB / 256; ++i) {
        const int j = i * 256 + tid;
        const int4 ob = *(const int4*)(pre + j * PRE_STRIDE + 12);
        const bool hit = (tx >= ob.x) & (tx <= ob.y) & (ty >= ob.z) & (ty <= ob.w);
        const unsigned long long m = __ballot(hit);
        if (lane == 0) { sh_cnt[i * 4 + w] = __popcll(m); sh_mask[i * 4 + w] = m; }
    }
    __syncthreads();

    // ---- deterministic prefix over the 32 (iter, wave) slots ----
    int cs[32];
    #pragma unroll
    for (int q = 0; q < 8; ++q) {
        const int4 v = ((const int4*)sh_cnt)[q];
        cs[q * 4 + 0] = v.x; cs[q * 4 + 1] = v.y;
        cs[q * 4 + 2] = v.z; cs[q * 4 + 3] = v.w;
    }
    int base[8];
    int n = 0;
    #pragma unroll
    for (int k = 0; k < 32; ++k) {
        if ((k & 3) == w) base[k >> 2] = n;
        n += cs[k];
    }
    const int lo = (ch * n) / NCHUNK;
    const int hi = ((ch + 1) * n) / NCHUNK;       // slice [lo, hi), size <= CAP

    // ---- pass 2: stage my slice's params (32 B packed) into LDS ----
    #pragma unroll
    for (int i = 0; i < NBLOB / 256; ++i) {
        const unsigned long long m = sh_mask[i * 4 + w];
        if ((m >> lane) & 1ull) {
            const int pos = base[i] + __popcll(m & ((1ull << lane) - 1ull));
            if (pos >= lo && pos < hi) {
                const float* p = pre + (i * 256 + tid) * PRE_STRIDE;
                HF c01, c2;
                c01.h = __floats2half2_rn(p[6], p[7]);
                c2.h  = __floats2half2_rn(p[8], 0.f);
                sh_rec[(pos - lo) * 2 + 0] = make_float4(p[0], p[1], p[2], p[3]);
                sh_rec[(pos - lo) * 2 + 1] = make_float4(p[4], p[5], c01.f, c2.f);
            }
        }
    }
    // pad slice to multiple of 4 with zero-records (g*color == 0 contribution)
    const int my_n0 = hi - lo;
    const int pad = (4 - (my_n0 & 3)) & 3;
    if (tid < pad) {
        const float4 z = make_float4(0.f, 0.f, 0.f, 0.f);
        sh_rec[(my_n0 + tid) * 2 + 0] = z;
        sh_rec[(my_n0 + tid) * 2 + 1] = z;
    }
    __syncthreads();
    const int my_n = my_n0 + pad;

    const int x  = tx * TILE_W + (tid & 31);
    const int y0 = ty * TILE_H + (tid >> 5);      // rows y0 + {0,8,16,24}
    const float fx  = (x + 0.5f) * (1.0f / RES);
    const float fy0 = (y0 + 0.5f) * (1.0f / RES);

    float ar0 = 0.f, ag0 = 0.f, ab0 = 0.f;
    float ar1 = 0.f, ag1 = 0.f, ab1 = 0.f;
    float ar2 = 0.f, ag2 = 0.f, ab2 = 0.f;
    float ar3 = 0.f, ag3 = 0.f, ab3 = 0.f;

    #pragma unroll 4
    for (int k = 0; k < my_n; ++k) {
        const float4 q0 = sh_rec[k * 2 + 0];      // px py a b
        const float4 q1 = sh_rec[k * 2 + 1];      // d e (cr,cg)h2 (cb,0)h2
        const float dx  = fx - q0.x;
        const float dyb = fy0 - q0.y;
        const float tu = q0.z * dx;
        const float tv = q1.x * dx;
        HF c01, c2; c01.f = q1.z; c2.f = q1.w;
        const float cr = __low2float(c01.h);
        const float cg = __high2float(c01.h);
        const float cb = __low2float(c2.h);
        float u, v, g;
        u = fmaf(q0.w, dyb, tu);
        v = fmaf(q1.y, dyb, tv);
        g = fast_exp2(-(u * u + v * v));
        ar0 += g * cr; ag0 += g * cg; ab0 += g * cb;
        u = fmaf(q0.w, dyb + ( 8.0f / RES), tu);
        v = fmaf(q1.y, dyb + ( 8.0f / RES), tv);
        g = fast_exp2(-(u * u + v * v));
        ar1 += g * cr; ag1 += g * cg; ab1 += g * cb;
        u = fmaf(q0.w, dyb + (16.0f / RES), tu);
        v = fmaf(q1.y, dyb + (16.0f / RES), tv);
        g = fast_exp2(-(u * u + v * v));
        ar2 += g * cr; ag2 += g * cg; ab2 += g * cb;
        u = fmaf(q0.w, dyb + (24.0f / RES), tu);
        v = fmaf(q1.y, dyb + (24.0f / RES), tv);
        g = fast_exp2(-(u * u + v * v));
        ar3 += g * cr; ag3 += g * cg; ab3 += g * cb;
    }

    float* dst = partial + (size_t)ch * IMG_FLOATS;
    int b0 = ((y0 +  0) * RES + x) * 3;
    dst[b0 + 0] = ar0; dst[b0 + 1] = ag0; dst[b0 + 2] = ab0;
    int b1 = ((y0 +  8) * RES + x) * 3;
    dst[b1 + 0] = ar1; dst[b1 + 1] = ag1; dst[b1 + 2] = ab1;
    int b2 = ((y0 + 16) * RES + x) * 3;
    dst[b2 + 0] = ar2; dst[b2 + 1] = ag2; dst[b2 + 2] = ab2;
    int b3 = ((y0 + 24) * RES + x) * 3;
    dst[b3 + 0] = ar3; dst[b3 + 1] = ag3; dst[b3 + 2] = ab3;
}

// out[i] = sum over the 8 partial images (float4-vectorized; 27 MB traffic).
__global__ __launch_bounds__(256) void reduce_kernel(const float4* __restrict__ partial,
                                                     float4* __restrict__ out) {
    const int i = blockIdx.x * 256 + threadIdx.x;
    float4 s = partial[i];
    #pragma unroll
    for (int c = 1; c < NCHUNK; ++c) {
        const float4 v = partial[(size_t)c * (IMG_FLOATS / 4) + i];
        s.x += v.x; s.y += v.y; s.z += v.z; s.w += v.w;
    }
    out[i] = s;
}

// Fallback if ws is too small (shouldn't trigger; observed ws ~268 MB):
// fused cull + LDS index list + scalar-load splat (R3 structure, ~52 us).
__global__ __launch_bounds__(256) void splat_fallback(const float* __restrict__ pre,
                                                      float* __restrict__ out) {
    __shared__ int sh_cnt;
    __shared__ int sh_list[NBLOB];
    const int tid = threadIdx.x;
    if (tid == 0) sh_cnt = 0;
    __syncthreads();
    const int tx = blockIdx.x, ty = blockIdx.y;
    const int lane = tid & 63;
    for (int j0 = 0; j0 < NBLOB; j0 += 256) {
        const int j = j0 + tid;
        const int4 ob = *(const int4*)(pre + j * PRE_STRIDE + 12);
        const bool hit = (tx >= ob.x) & (tx <= ob.y) & (ty >= ob.z) & (ty <= ob.w);
        const unsigned long long m = __ballot(hit);
        int base = 0;
        if (lane == 0 && m) base = atomicAdd(&sh_cnt, __popcll(m));
        base = __builtin_amdgcn_readfirstlane(base);
        if (hit) sh_list[base + __popcll(m & ((1ull << lane) - 1ull))] = j;
    }
    __syncthreads();
    const int n = sh_cnt;
    const int x = tx * TILE_W + (tid & 31);
    const int y = ty * TILE_H + (tid >> 5) * 4;   // 4 consecutive rows? no: stride 8
    const float fx = (x + 0.5f) * (1.0f / RES);
    float acc[4][3] = {};
    for (int k = 0; k < n; ++k) {
        const int j = __builtin_amdgcn_readfirstlane(sh_list[k]);
        const float* p = pre + j * PRE_STRIDE;
        const float dx = fx - p[0];
        #pragma unroll
        for (int r = 0; r < 4; ++r) {
            const float fy = (ty * TILE_H + (tid >> 5) + r * 8 + 0.5f) * (1.0f / RES);
            const float dy = fy - p[1];
            const float u = p[2] * dx + p[3] * dy;
            const float v = p[4] * dx + p[5] * dy;
            const float g = fast_exp2(-(u * u + v * v));
            acc[r][0] += g * p[6]; acc[r][1] += g * p[7]; acc[r][2] += g * p[8];
        }
    }
    #pragma unroll
    for (int r = 0; r < 4; ++r) {
        const int yy = ty * TILE_H + (tid >> 5) + r * 8;
        const int b = (yy * RES + x) * 3;
        out[b + 0] = acc[r][0]; out[b + 1] = acc[r][1]; out[b + 2] = acc[r][2];
    }
}

extern "C" void kernel_launch(void* const* d_in, const int* in_sizes, int n_in,
                              void* d_out, int out_size, void* d_ws, size_t ws_size,
                              hipStream_t stream) {
    const float* blobs = (const float*)d_in[0];
    float* out = (float*)d_out;

    char* ws = (char*)d_ws;
    float* pre = (float*)ws;
    size_t off = ((size_t)NBLOB * PRE_STRIDE * 4 + 255) & ~(size_t)255;  // 128 KB
    float* partial = (float*)(ws + off);
    const size_t need = off + (size_t)NCHUNK * IMG_FLOATS * 4;           // ~24 MB

    hipLaunchKernelGGL(pre_kernel, dim3(NBLOB / 256), dim3(256), 0, stream,
                       blobs, pre);
    if (ws_size >= need) {
        hipLaunchKernelGGL(splat_kernel, dim3(TX_N, TY_N, NCHUNK), dim3(256), 0,
                           stream, pre, partial);
        hipLaunchKernelGGL(reduce_kernel, dim3(IMG_FLOATS / 1024), dim3(256), 0,
                           stream, (const float4*)partial, (float4*)out);
    } else {
        hipLaunchKernelGGL(splat_fallback, dim3(TX_N, TY_N), dim3(256), 0,
                           stream, pre, out);
    }
}

// Round 8
// 91.709 us; speedup vs baseline: 1.2440x; 1.0124x over previous
//
#include <hip/hip_runtime.h>
#include <hip/hip_fp16.h>
#include <math.h>

#define RES     512
#define NBLOB   2048
#define TILE_W  32
#define TILE_H  32
#define TX_N    (RES / TILE_W)   // 16
#define TY_N    (RES / TILE_H)   // 16
#define NTILE   (TX_N * TY_N)    // 256
#define NCHUNK  8                // list-slices per tile -> 2048 splat blocks
#define CAP     256              // slice size <= ceil(NBLOB/NCHUNK)
#define PRE_STRIDE 8             // floats per blob: [px py a b][d e (cr,cg)h2 (cb,0)h2]
#define IMG_FLOATS (RES * RES * 3)
#define CULL_R5 4.9956f          // sqrt(18)/K : cutoff where g < 2^-18

union HF { __half2 h; float f; };

__device__ __forceinline__ float fast_exp2(float x) {
#if __has_builtin(__builtin_amdgcn_exp2f)
    return __builtin_amdgcn_exp2f(x);
#else
    return exp2f(x);
#endif
}

// One block per 32x32 tile. Fuses per-blob preprocessing (rotation/scale/exp
// constant folded into a 2x2 matrix; colors packed to half2) with the tile
// cull: writes this tile's survivor list as u16 blob indices + count. Each
// block computes all 2048 blobs' params (cheap: 8/thread, hw sin/cos in
// revolutions) and block t persists params for blobs [8t, 8t+8) to pre[].
__global__ __launch_bounds__(256) void bin_kernel(const float* __restrict__ blobs,
                                                  float* __restrict__ pre,
                                                  unsigned short* __restrict__ lists,
                                                  int* __restrict__ counts) {
    __shared__ int sh_cnt;
    const int tid  = threadIdx.x;
    const int lane = tid & 63;
    if (tid == 0) sh_cnt = 0;
    __syncthreads();
    const int tx = blockIdx.x, ty = blockIdx.y;
    const int t = ty * TX_N + tx;
    unsigned short* mylist = lists + (size_t)t * NBLOB;
    const float K = 0.84932184f;  // sqrt(0.5 * log2(e))

    #pragma unroll
    for (int k = 0; k < NBLOB / 256; ++k) {
        const int j = k * 256 + tid;
        const float4 b0 = ((const float4*)(blobs + j * 8))[0];  // px py sx sy
        const float4 b1 = ((const float4*)(blobs + j * 8))[1];  // rot cr cg cb
        float s, c;
#if __has_builtin(__builtin_amdgcn_sinf) && __has_builtin(__builtin_amdgcn_cosf)
        float r = b1.x * 0.15915494309189535f;  // rot / 2pi (v_sin takes revolutions)
        r -= floorf(r);
        s = __builtin_amdgcn_sinf(r);
        c = __builtin_amdgcn_cosf(r);
#else
        s = sinf(b1.x); c = cosf(b1.x);
#endif
        // persist params for my 8 assigned blobs
        if ((j >> 3) == t) {
            const float isx = K / b0.z, isy = K / b0.w;
            HF c01, c2;
            c01.h = __floats2half2_rn(b1.y, b1.z);
            c2.h  = __floats2half2_rn(b1.w, 0.f);
            float4* o = (float4*)(pre + j * PRE_STRIDE);
            o[0] = make_float4(b0.x, b0.y, c * isx, s * isx);
            o[1] = make_float4(-s * isy, c * isy, c01.f, c2.f);
        }
        // conservative tile bbox of the cull ellipse
        const float hx = CULL_R5 * sqrtf(c * c * b0.z * b0.z + s * s * b0.w * b0.w);
        const float hy = CULL_R5 * sqrtf(s * s * b0.z * b0.z + c * c * b0.w * b0.w);
        const int tx0 = max(0,        (int)floorf(((b0.x - hx) * RES - 0.5f) * (1.0f / TILE_W)));
        const int tx1 = min(TX_N - 1, (int)floorf(((b0.x + hx) * RES - 0.5f) * (1.0f / TILE_W)));
        const int ty0 = max(0,        (int)floorf(((b0.y - hy) * RES - 0.5f) * (1.0f / TILE_H)));
        const int ty1 = min(TY_N - 1, (int)floorf(((b0.y + hy) * RES - 0.5f) * (1.0f / TILE_H)));
        const bool hit = (tx >= tx0) & (tx <= tx1) & (ty >= ty0) & (ty <= ty1);
        const unsigned long long m = __ballot(hit);
        int base = 0;
        if (lane == 0 && m) base = atomicAdd(&sh_cnt, __popcll(m));
        base = __builtin_amdgcn_readfirstlane(base);
        if (hit) mylist[base + __popcll(m & ((1ull << lane) - 1ull))] = (unsigned short)j;
    }
    __syncthreads();
    if (tid == 0) counts[t] = sh_cnt;
}

// One block per (tile, 1/8 slice of its prebuilt list). Prologue is ~500 cyc:
// coalesced u16 index load + 32 B param gather from the 64 KB LLC-hot pre[],
// one barrier. Main loop: 4 px/thread (rows +0,+8,+16,+24), LDS-broadcast
// records, plain stores to this slice's private partial image.
__global__ __launch_bounds__(256, 8) void splat_kernel(const float* __restrict__ pre,
                                                       const unsigned short* __restrict__ lists,
                                                       const int* __restrict__ counts,
                                                       float* __restrict__ partial) {
    __shared__ float4 sh_rec[2 * (CAP + 4)];

    const int tid = threadIdx.x;
    const int tx = blockIdx.x, ty = blockIdx.y, ch = blockIdx.z;
    const int t = ty * TX_N + tx;
    const int n = counts[t];
    const int lo = (ch * n) >> 3;          // NCHUNK == 8
    const int hi = ((ch + 1) * n) >> 3;
    const int my_n0 = hi - lo;
    const int pad = (4 - (my_n0 & 3)) & 3;

    if (tid < my_n0) {
        const int idx = lists[(size_t)t * NBLOB + lo + tid];
        const float4* pp = (const float4*)(pre + idx * PRE_STRIDE);
        sh_rec[tid * 2 + 0] = pp[0];
        sh_rec[tid * 2 + 1] = pp[1];
    } else if (tid < my_n0 + pad) {
        // zero-record: g=1 * color=0 -> contributes nothing
        const float4 z = make_float4(0.f, 0.f, 0.f, 0.f);
        sh_rec[tid * 2 + 0] = z;
        sh_rec[tid * 2 + 1] = z;
    }
    __syncthreads();
    const int my_n = my_n0 + pad;

    const int x  = tx * TILE_W + (tid & 31);
    const int y0 = ty * TILE_H + (tid >> 5);      // rows y0 + {0,8,16,24}
    const float fx  = (x + 0.5f) * (1.0f / RES);
    const float fy0 = (y0 + 0.5f) * (1.0f / RES);

    float ar0 = 0.f, ag0 = 0.f, ab0 = 0.f;
    float ar1 = 0.f, ag1 = 0.f, ab1 = 0.f;
    float ar2 = 0.f, ag2 = 0.f, ab2 = 0.f;
    float ar3 = 0.f, ag3 = 0.f, ab3 = 0.f;

    #pragma unroll 4
    for (int k = 0; k < my_n; ++k) {
        const float4 q0 = sh_rec[k * 2 + 0];      // px py a b
        const float4 q1 = sh_rec[k * 2 + 1];      // d e (cr,cg)h2 (cb,0)h2
        const float dx  = fx - q0.x;
        const float dyb = fy0 - q0.y;
        const float tu = q0.z * dx;
        const float tv = q1.x * dx;
        HF c01, c2; c01.f = q1.z; c2.f = q1.w;
        const float cr = __low2float(c01.h);
        const float cg = __high2float(c01.h);
        const float cb = __low2float(c2.h);
        float u, v, g;
        u = fmaf(q0.w, dyb, tu);
        v = fmaf(q1.y, dyb, tv);
        g = fast_exp2(-(u * u + v * v));
        ar0 += g * cr; ag0 += g * cg; ab0 += g * cb;
        u = fmaf(q0.w, dyb + ( 8.0f / RES), tu);
        v = fmaf(q1.y, dyb + ( 8.0f / RES), tv);
        g = fast_exp2(-(u * u + v * v));
        ar1 += g * cr; ag1 += g * cg; ab1 += g * cb;
        u = fmaf(q0.w, dyb + (16.0f / RES), tu);
        v = fmaf(q1.y, dyb + (16.0f / RES), tv);
        g = fast_exp2(-(u * u + v * v));
        ar2 += g * cr; ag2 += g * cg; ab2 += g * cb;
        u = fmaf(q0.w, dyb + (24.0f / RES), tu);
        v = fmaf(q1.y, dyb + (24.0f / RES), tv);
        g = fast_exp2(-(u * u + v * v));
        ar3 += g * cr; ag3 += g * cg; ab3 += g * cb;
    }

    float* dst = partial + (size_t)ch * IMG_FLOATS;
    int b0 = ((y0 +  0) * RES + x) * 3;
    dst[b0 + 0] = ar0; dst[b0 + 1] = ag0; dst[b0 + 2] = ab0;
    int b1 = ((y0 +  8) * RES + x) * 3;
    dst[b1 + 0] = ar1; dst[b1 + 1] = ag1; dst[b1 + 2] = ab1;
    int b2 = ((y0 + 16) * RES + x) * 3;
    dst[b2 + 0] = ar2; dst[b2 + 1] = ag2; dst[b2 + 2] = ab2;
    int b3 = ((y0 + 24) * RES + x) * 3;
    dst[b3 + 0] = ar3; dst[b3 + 1] = ag3; dst[b3 + 2] = ab3;
}

// out[i] = sum of the 8 partial images (float4-vectorized, ~27 MB traffic).
__global__ __launch_bounds__(256) void reduce_kernel(const float4* __restrict__ partial,
                                                     float4* __restrict__ out) {
    const int i = blockIdx.x * 256 + threadIdx.x;
    float4 s = partial[i];
    #pragma unroll
    for (int c = 1; c < NCHUNK; ++c) {
        const float4 v = partial[(size_t)c * (IMG_FLOATS / 4) + i];
        s.x += v.x; s.y += v.y; s.z += v.z; s.w += v.w;
    }
    out[i] = s;
}

// Never-taken safety net if ws is too small (observed ws ~268 MB, need ~25 MB):
// naive all-pairs splat straight from blobs.
__global__ __launch_bounds__(256) void splat_naive(const float* __restrict__ blobs,
                                                   float* __restrict__ out) {
    const int x = blockIdx.x * 32 + (threadIdx.x & 31);
    const int y = blockIdx.y * 8 + (threadIdx.x >> 5);
    const float fx = (x + 0.5f) * (1.0f / RES);
    const float fy = (y + 0.5f) * (1.0f / RES);
    const float K = 0.84932184f;
    float ar = 0.f, ag = 0.f, ab = 0.f;
    for (int j = 0; j < NBLOB; ++j) {
        const float* bp = blobs + j * 8;
        const float s = sinf(bp[4]), c = cosf(bp[4]);
        const float isx = K / bp[2], isy = K / bp[3];
        const float dx = fx - bp[0], dy = fy - bp[1];
        const float u = (c * dx + s * dy) * isx;
        const float v = (-s * dx + c * dy) * isy;
        const float g = fast_exp2(-(u * u + v * v));
        ar += g * bp[5]; ag += g * bp[6]; ab += g * bp[7];
    }
    const int b = (y * RES + x) * 3;
    out[b + 0] = ar; out[b + 1] = ag; out[b + 2] = ab;
}

extern "C" void kernel_launch(void* const* d_in, const int* in_sizes, int n_in,
                              void* d_out, int out_size, void* d_ws, size_t ws_size,
                              hipStream_t stream) {
    const float* blobs = (const float*)d_in[0];
    float* out = (float*)d_out;

    char* ws = (char*)d_ws;
    float* pre = (float*)ws;                                   // 64 KB
    size_t off = ((size_t)NBLOB * PRE_STRIDE * 4 + 255) & ~(size_t)255;
    int* counts = (int*)(ws + off); off += NTILE * 4;          // 1 KB
    off = (off + 255) & ~(size_t)255;
    unsigned short* lists = (unsigned short*)(ws + off);       // 1 MB
    off += (size_t)NTILE * NBLOB * 2;
    off = (off + 255) & ~(size_t)255;
    float* partial = (float*)(ws + off);                       // 24 MB
    const size_t need = off + (size_t)NCHUNK * IMG_FLOATS * 4;

    if (ws_size >= need) {
        hipLaunchKernelGGL(bin_kernel, dim3(TX_N, TY_N), dim3(256), 0, stream,
                           blobs, pre, lists, counts);
        hipLaunchKernelGGL(splat_kernel, dim3(TX_N, TY_N, NCHUNK), dim3(256), 0,
                           stream, pre, lists, counts, partial);
        hipLaunchKernelGGL(reduce_kernel, dim3(IMG_FLOATS / 1024), dim3(256), 0,
                           stream, (const float4*)partial, (float4*)out);
    } else {
        hipLaunchKernelGGL(splat_naive, dim3(RES / 32, RES / 8), dim3(256), 0,
                           stream, blobs, out);
    }
}

// Round 9
// 90.374 us; speedup vs baseline: 1.2624x; 1.0148x over previous
//
#include <hip/hip_runtime.h>
#include <hip/hip_fp16.h>
#include <math.h>

#define RES     512
#define NBLOB   2048
#define TILE_W  32
#define TILE_H  32
#define TX_N    (RES / TILE_W)   // 16
#define TY_N    (RES / TILE_H)   // 16
#define NTILE   (TX_N * TY_N)    // 256
#define NCHUNK  8                // list-slices per tile -> 2048 splat blocks
#define CAP     256              // slice size <= ceil(NBLOB/NCHUNK)
#define PRE_STRIDE 8             // floats per blob: [px py a b][d e (cr,cg)h2 (cb,0)h2]
#define IMG_FLOATS (RES * RES * 3)
#define CULL_R5 4.9956f          // sqrt(18)/K : cutoff where g < 2^-18

union HF { __half2 h; float f; };

__device__ __forceinline__ float fast_exp2(float x) {
#if __has_builtin(__builtin_amdgcn_exp2f)
    return __builtin_amdgcn_exp2f(x);
#else
    return exp2f(x);
#endif
}

// One block per 32x32 tile. Fuses per-blob preprocessing (rotation/scale/exp
// constant folded into a 2x2 matrix; colors packed to half2) with the tile
// cull: writes this tile's survivor list as u16 blob indices + count. Block t
// also persists params for blobs [8t, 8t+8) to pre[].
__global__ __launch_bounds__(256) void bin_kernel(const float* __restrict__ blobs,
                                                  float* __restrict__ pre,
                                                  unsigned short* __restrict__ lists,
                                                  int* __restrict__ counts) {
    __shared__ int sh_cnt;
    const int tid  = threadIdx.x;
    const int lane = tid & 63;
    if (tid == 0) sh_cnt = 0;
    __syncthreads();
    const int tx = blockIdx.x, ty = blockIdx.y;
    const int t = ty * TX_N + tx;
    unsigned short* mylist = lists + (size_t)t * NBLOB;
    const float K = 0.84932184f;  // sqrt(0.5 * log2(e))

    #pragma unroll
    for (int k = 0; k < NBLOB / 256; ++k) {
        const int j = k * 256 + tid;
        const float4 b0 = ((const float4*)(blobs + j * 8))[0];  // px py sx sy
        const float4 b1 = ((const float4*)(blobs + j * 8))[1];  // rot cr cg cb
        float s, c;
#if __has_builtin(__builtin_amdgcn_sinf) && __has_builtin(__builtin_amdgcn_cosf)
        float r = b1.x * 0.15915494309189535f;  // rot / 2pi (v_sin takes revolutions)
        r -= floorf(r);
        s = __builtin_amdgcn_sinf(r);
        c = __builtin_amdgcn_cosf(r);
#else
        s = sinf(b1.x); c = cosf(b1.x);
#endif
        // persist params for my 8 assigned blobs
        if ((j >> 3) == t) {
            const float isx = K / b0.z, isy = K / b0.w;
            HF c01, c2;
            c01.h = __floats2half2_rn(b1.y, b1.z);
            c2.h  = __floats2half2_rn(b1.w, 0.f);
            float4* o = (float4*)(pre + j * PRE_STRIDE);
            o[0] = make_float4(b0.x, b0.y, c * isx, s * isx);
            o[1] = make_float4(-s * isy, c * isy, c01.f, c2.f);
        }
        // conservative tile bbox of the cull ellipse
        const float hx = CULL_R5 * sqrtf(c * c * b0.z * b0.z + s * s * b0.w * b0.w);
        const float hy = CULL_R5 * sqrtf(s * s * b0.z * b0.z + c * c * b0.w * b0.w);
        const int tx0 = max(0,        (int)floorf(((b0.x - hx) * RES - 0.5f) * (1.0f / TILE_W)));
        const int tx1 = min(TX_N - 1, (int)floorf(((b0.x + hx) * RES - 0.5f) * (1.0f / TILE_W)));
        const int ty0 = max(0,        (int)floorf(((b0.y - hy) * RES - 0.5f) * (1.0f / TILE_H)));
        const int ty1 = min(TY_N - 1, (int)floorf(((b0.y + hy) * RES - 0.5f) * (1.0f / TILE_H)));
        const bool hit = (tx >= tx0) & (tx <= tx1) & (ty >= ty0) & (ty <= ty1);
        const unsigned long long m = __ballot(hit);
        int base = 0;
        if (lane == 0 && m) base = atomicAdd(&sh_cnt, __popcll(m));
        base = __builtin_amdgcn_readfirstlane(base);
        if (hit) mylist[base + __popcll(m & ((1ull << lane) - 1ull))] = (unsigned short)j;
    }
    __syncthreads();
    if (tid == 0) counts[t] = sh_cnt;
}

// One block per (slice, tile). ch is the FASTEST grid dimension so the
// breadth-first block->CU round-robin gives each CU slices from 8 different
// tiles (spaced 32 apart in tile id) instead of all 8 slices of one tile —
// per-CU work ~= mean tile count, not max (R8's grid put tile t's whole list
// on CU t: kernel ran at the heaviest tile's pace, ~2.3x mean).
__global__ __launch_bounds__(256, 8) void splat_kernel(const float* __restrict__ pre,
                                                       const unsigned short* __restrict__ lists,
                                                       const int* __restrict__ counts,
                                                       float* __restrict__ partial) {
    __shared__ float4 sh_rec[2 * (CAP + 4)];

    const int tid = threadIdx.x;
    const int ch = blockIdx.x, tx = blockIdx.y, ty = blockIdx.z;
    const int t = ty * TX_N + tx;
    const int n = counts[t];
    const int lo = (ch * n) >> 3;          // NCHUNK == 8
    const int hi = ((ch + 1) * n) >> 3;
    const int my_n0 = hi - lo;
    const int pad = (4 - (my_n0 & 3)) & 3;

    if (tid < my_n0) {
        const int idx = lists[(size_t)t * NBLOB + lo + tid];
        const float4* pp = (const float4*)(pre + idx * PRE_STRIDE);
        sh_rec[tid * 2 + 0] = pp[0];
        sh_rec[tid * 2 + 1] = pp[1];
    } else if (tid < my_n0 + pad) {
        // zero-record: g=1 * color=0 -> contributes nothing
        const float4 z = make_float4(0.f, 0.f, 0.f, 0.f);
        sh_rec[tid * 2 + 0] = z;
        sh_rec[tid * 2 + 1] = z;
    }
    __syncthreads();
    const int my_n = my_n0 + pad;

    const int x  = tx * TILE_W + (tid & 31);
    const int y0 = ty * TILE_H + (tid >> 5);      // rows y0 + {0,8,16,24}
    const float fx  = (x + 0.5f) * (1.0f / RES);
    const float fy0 = (y0 + 0.5f) * (1.0f / RES);

    float ar0 = 0.f, ag0 = 0.f, ab0 = 0.f;
    float ar1 = 0.f, ag1 = 0.f, ab1 = 0.f;
    float ar2 = 0.f, ag2 = 0.f, ab2 = 0.f;
    float ar3 = 0.f, ag3 = 0.f, ab3 = 0.f;

    #pragma unroll 4
    for (int k = 0; k < my_n; ++k) {
        const float4 q0 = sh_rec[k * 2 + 0];      // px py a b
        const float4 q1 = sh_rec[k * 2 + 1];      // d e (cr,cg)h2 (cb,0)h2
        const float dx  = fx - q0.x;
        const float dyb = fy0 - q0.y;
        const float tu = q0.z * dx;
        const float tv = q1.x * dx;
        HF c01, c2; c01.f = q1.z; c2.f = q1.w;
        const float cr = __low2float(c01.h);
        const float cg = __high2float(c01.h);
        const float cb = __low2float(c2.h);
        float u, v, g;
        u = fmaf(q0.w, dyb, tu);
        v = fmaf(q1.y, dyb, tv);
        g = fast_exp2(-(u * u + v * v));
        ar0 += g * cr; ag0 += g * cg; ab0 += g * cb;
        u = fmaf(q0.w, dyb + ( 8.0f / RES), tu);
        v = fmaf(q1.y, dyb + ( 8.0f / RES), tv);
        g = fast_exp2(-(u * u + v * v));
        ar1 += g * cr; ag1 += g * cg; ab1 += g * cb;
        u = fmaf(q0.w, dyb + (16.0f / RES), tu);
        v = fmaf(q1.y, dyb + (16.0f / RES), tv);
        g = fast_exp2(-(u * u + v * v));
        ar2 += g * cr; ag2 += g * cg; ab2 += g * cb;
        u = fmaf(q0.w, dyb + (24.0f / RES), tu);
        v = fmaf(q1.y, dyb + (24.0f / RES), tv);
        g = fast_exp2(-(u * u + v * v));
        ar3 += g * cr; ag3 += g * cg; ab3 += g * cb;
    }

    float* dst = partial + (size_t)ch * IMG_FLOATS;
    int b0 = ((y0 +  0) * RES + x) * 3;
    dst[b0 + 0] = ar0; dst[b0 + 1] = ag0; dst[b0 + 2] = ab0;
    int b1 = ((y0 +  8) * RES + x) * 3;
    dst[b1 + 0] = ar1; dst[b1 + 1] = ag1; dst[b1 + 2] = ab1;
    int b2 = ((y0 + 16) * RES + x) * 3;
    dst[b2 + 0] = ar2; dst[b2 + 1] = ag2; dst[b2 + 2] = ab2;
    int b3 = ((y0 + 24) * RES + x) * 3;
    dst[b3 + 0] = ar3; dst[b3 + 1] = ag3; dst[b3 + 2] = ab3;
}

// out[i] = sum of the 8 partial images (float4-vectorized, ~27 MB traffic).
__global__ __launch_bounds__(256) void reduce_kernel(const float4* __restrict__ partial,
                                                     float4* __restrict__ out) {
    const int i = blockIdx.x * 256 + threadIdx.x;
    float4 s = partial[i];
    #pragma unroll
    for (int c = 1; c < NCHUNK; ++c) {
        const float4 v = partial[(size_t)c * (IMG_FLOATS / 4) + i];
        s.x += v.x; s.y += v.y; s.z += v.z; s.w += v.w;
    }
    out[i] = s;
}

// Never-taken safety net if ws is too small (observed ws ~268 MB, need ~25 MB).
__global__ __launch_bounds__(256) void splat_naive(const float* __restrict__ blobs,
                                                   float* __restrict__ out) {
    const int x = blockIdx.x * 32 + (threadIdx.x & 31);
    const int y = blockIdx.y * 8 + (threadIdx.x >> 5);
    const float fx = (x + 0.5f) * (1.0f / RES);
    const float fy = (y + 0.5f) * (1.0f / RES);
    const float K = 0.84932184f;
    float ar = 0.f, ag = 0.f, ab = 0.f;
    for (int j = 0; j < NBLOB; ++j) {
        const float* bp = blobs + j * 8;
        const float s = sinf(bp[4]), c = cosf(bp[4]);
        const float isx = K / bp[2], isy = K / bp[3];
        const float dx = fx - bp[0], dy = fy - bp[1];
        const float u = (c * dx + s * dy) * isx;
        const float v = (-s * dx + c * dy) * isy;
        const float g = fast_exp2(-(u * u + v * v));
        ar += g * bp[5]; ag += g * bp[6]; ab += g * bp[7];
    }
    const int b = (y * RES + x) * 3;
    out[b + 0] = ar; out[b + 1] = ag; out[b + 2] = ab;
}

extern "C" void kernel_launch(void* const* d_in, const int* in_sizes, int n_in,
                              void* d_out, int out_size, void* d_ws, size_t ws_size,
                              hipStream_t stream) {
    const float* blobs = (const float*)d_in[0];
    float* out = (float*)d_out;

    char* ws = (char*)d_ws;
    float* pre = (float*)ws;                                   // 64 KB
    size_t off = ((size_t)NBLOB * PRE_STRIDE * 4 + 255) & ~(size_t)255;
    int* counts = (int*)(ws + off); off += NTILE * 4;          // 1 KB
    off = (off + 255) & ~(size_t)255;
    unsigned short* lists = (unsigned short*)(ws + off);       // 1 MB
    off += (size_t)NTILE * NBLOB * 2;
    off = (off + 255) & ~(size_t)255;
    float* partial = (float*)(ws + off);                       // 24 MB
    const size_t need = off + (size_t)NCHUNK * IMG_FLOATS * 4;

    if (ws_size >= need) {
        hipLaunchKernelGGL(bin_kernel, dim3(TX_N, TY_N), dim3(256), 0, stream,
                           blobs, pre, lists, counts);
        // ch fastest: balanced block->CU assignment (see splat_kernel comment)
        hipLaunchKernelGGL(splat_kernel, dim3(NCHUNK, TX_N, TY_N), dim3(256), 0,
                           stream, pre, lists, counts, partial);
        hipLaunchKernelGGL(reduce_kernel, dim3(IMG_FLOATS / 1024), dim3(256), 0,
                           stream, (const float4*)partial, (float4*)out);
    } else {
        hipLaunchKernelGGL(splat_naive, dim3(RES / 32, RES / 8), dim3(256), 0,
                           stream, blobs, out);
    }
}